// Round 5
// baseline (1561.050 us; speedup 1.0000x reference)
//
#include <hip/hip_runtime.h>
#include <hip/hip_bf16.h>
#include <cmath>

typedef __bf16 bf16_t;
typedef bf16_t bf16x8 __attribute__((ext_vector_type(8)));
typedef float f32x4 __attribute__((ext_vector_type(4)));
typedef unsigned long long ull_t;

#define B_ 32
#define T_ 64
#define D_ 512
#define H_ 1024
#define V_ 20000

// ---------------- cast ----------------
__global__ __launch_bounds__(256) void k_cast(const float* __restrict__ s,
                                              bf16_t* __restrict__ d, int n8) {
    int i = blockIdx.x * 256 + threadIdx.x;
    if (i >= n8) return;
    const f32x4* sv = (const f32x4*)s + (size_t)i * 2;
    f32x4 v0 = sv[0], v1 = sv[1];
    bf16x8 o;
    o[0] = (bf16_t)v0[0]; o[1] = (bf16_t)v0[1]; o[2] = (bf16_t)v0[2]; o[3] = (bf16_t)v0[3];
    o[4] = (bf16_t)v1[0]; o[5] = (bf16_t)v1[1]; o[6] = (bf16_t)v1[2]; o[7] = (bf16_t)v1[3];
    *((bf16x8*)d + i) = o;
}

// ---------------- async global->LDS helper ----------------
__device__ __forceinline__ void gl_lds16(const bf16_t* g, bf16_t* l) {
    __builtin_amdgcn_global_load_lds(
        (const __attribute__((address_space(1))) unsigned int*)g,
        (__attribute__((address_space(3))) unsigned int*)l, 16, 0, 0);
}

// coherent (agent-scope, L2-bypassing) 16-B load as 2x8B atomics
__device__ __forceinline__ bf16x8 cload16(const bf16_t* p) {
    union { ull_t u[2]; bf16x8 v; } r;
    r.u[0] = __hip_atomic_load((const ull_t*)p,     __ATOMIC_RELAXED, __HIP_MEMORY_SCOPE_AGENT);
    r.u[1] = __hip_atomic_load((const ull_t*)p + 1, __ATOMIC_RELAXED, __HIP_MEMORY_SCOPE_AGENT);
    return r.v;
}

// ---------------- tiled GEMM: out[M x N] = A[M x K] * Bt[N x K]^T (+bias, +LSE partials) ----
// 128x128 block tile, BK=64, 4 waves (2x2), 4x4 fragments/wave, LDS-staged.
// XCD-aware bijective swizzle (grid divisible by 8; cpx = grid/8).
// If LSE: also emits per-(row, col-block) (max, sumexp) partials to `part`.
template<bool EDGE, bool BIAS, bool LSE>
__global__ __launch_bounds__(256) void k_gemm_t(const bf16_t* __restrict__ A, int lda,
                                                const bf16_t* __restrict__ Bt, int ldb,
                                                int nkt, const float* __restrict__ bias,
                                                float* __restrict__ out, int ldo,
                                                int nmax, int nbn, int cpx,
                                                float* __restrict__ part) {
    __shared__ bf16_t lA[128 * 64];
    __shared__ bf16_t lB[128 * 64];
    __shared__ float lds_ls[128][2][2];
    int bid = (blockIdx.x & 7) * cpx + (blockIdx.x >> 3);
    int bn = bid % nbn, bm = bid / nbn;
    int tid = threadIdx.x, w = tid >> 6, l = tid & 63;
    int wm = w >> 1, wn = w & 1;
    int lr = l & 15, lk = (l >> 4) << 3;
    int r0 = bm << 7, c0 = bn << 7;
    int chunkrow = l >> 3;
    int chunkcol = (l & 7) << 3;

    const bf16_t* srcA[4];
    const bf16_t* srcB[4];
#pragma unroll
    for (int i = 0; i < 4; ++i) {
        int rowt = ((w << 2) + i) << 3;
        int ra = r0 + rowt + chunkrow;
        srcA[i] = A + (size_t)ra * lda + chunkcol;
        int rb = c0 + rowt + chunkrow;
        if (EDGE) rb = rb < nmax ? rb : nmax - 1;
        srcB[i] = Bt + (size_t)rb * ldb + chunkcol;
    }

    f32x4 acc[4][4] = {};
    for (int kt = 0; kt < nkt; ++kt) {
        __syncthreads();
#pragma unroll
        for (int i = 0; i < 4; ++i) {
            gl_lds16(srcA[i] + (kt << 6), lA + ((((w << 2) + i)) << 9));
            gl_lds16(srcB[i] + (kt << 6), lB + ((((w << 2) + i)) << 9));
        }
        __syncthreads();
#pragma unroll
        for (int kk = 0; kk < 2; ++kk) {
            bf16x8 af[4], bfr[4];
#pragma unroll
            for (int i = 0; i < 4; ++i)
                af[i] = *(const bf16x8*)&lA[(((wm << 6) + (i << 4) + lr) << 6) + (kk << 5) + lk];
#pragma unroll
            for (int j = 0; j < 4; ++j)
                bfr[j] = *(const bf16x8*)&lB[(((wn << 6) + (j << 4) + lr) << 6) + (kk << 5) + lk];
#pragma unroll
            for (int i = 0; i < 4; ++i)
#pragma unroll
                for (int j = 0; j < 4; ++j)
                    acc[i][j] = __builtin_amdgcn_mfma_f32_16x16x32_bf16(af[i], bfr[j], acc[i][j], 0, 0, 0);
        }
    }

    int crow = (l >> 4) << 2;
    float bl[4]; int colv[4]; bool ok[4];
#pragma unroll
    for (int j = 0; j < 4; ++j) {
        int col = c0 + (wn << 6) + (j << 4) + lr;
        colv[j] = col;
        ok[j] = (!EDGE) || (col < nmax);
        bl[j] = (BIAS && ok[j]) ? bias[col] : 0.f;
    }
#pragma unroll
    for (int i = 0; i < 4; ++i) {
#pragma unroll
        for (int r = 0; r < 4; ++r) {
            int rowloc = (wm << 6) + (i << 4) + crow + r;
            int row = r0 + rowloc;
            float v[4]; float mx = -1e30f;
#pragma unroll
            for (int j = 0; j < 4; ++j) {
                if (ok[j]) {
                    v[j] = acc[i][j][r] + bl[j];
                    out[(size_t)row * ldo + colv[j]] = v[j];
                    mx = fmaxf(mx, v[j]);
                }
            }
            if (LSE) {
                float sm = 0.f;
#pragma unroll
                for (int j = 0; j < 4; ++j)
                    if (ok[j]) sm += __expf(v[j] - mx);
                // reduce (mx, sm) across the 16-lane row group
#pragma unroll
                for (int off = 1; off < 16; off <<= 1) {
                    float m2 = __shfl_xor(mx, off);
                    float s2 = __shfl_xor(sm, off);
                    float nm = fmaxf(mx, m2);
                    sm = sm * __expf(mx - nm) + s2 * __expf(m2 - nm);
                    mx = nm;
                }
                if ((l & 15) == 0) { lds_ls[rowloc][wn][0] = mx; lds_ls[rowloc][wn][1] = sm; }
            }
        }
    }
    if (LSE) {
        __syncthreads();
        if (tid < 128) {
            float m0 = lds_ls[tid][0][0], s0 = lds_ls[tid][0][1];
            float m1 = lds_ls[tid][1][0], s1 = lds_ls[tid][1][1];
            float nm = fmaxf(m0, m1);
            float s = s0 * __expf(m0 - nm) + s1 * __expf(m1 - nm);
            float* pp = part + ((size_t)(r0 + tid) * nbn + bn) * 2;
            pp[0] = nm; pp[1] = s;
        }
    }
}

// ---------------- persistent LSTM recurrence, flag-poll barrier ----------------
// 64 blocks x 512 threads (cooperative for co-residency; no grid.sync).
// Block owns 16 H-cols x 4 gates = 64 W_hh rows; full-K B-fragments persist in
// registers (128 VGPR/lane, duplicated across batch halves). Each wave computes
// one full-K 16x16 gate tile -> no cross-wave reduce. Barrier: per-block
// monotonic flag (own cacheline) + 64-wide parallel poll.
__global__ __launch_bounds__(512, 2) void k_recur(const bf16_t* __restrict__ h0,
                                                  const bf16_t* __restrict__ Whh,  // [4096][1024]
                                                  const float* __restrict__ xw,    // [2048][4096]
                                                  const float* __restrict__ bih,
                                                  const float* __restrict__ bhh,
                                                  bf16_t* __restrict__ h_all,      // [2048][1024], m=b*64+t
                                                  unsigned* __restrict__ flags) {  // [64] stride-16 u32
    __shared__ float lds_g[32][68];
    int tid = threadIdx.x, w = tid >> 6, l = tid & 63;
    int bid = blockIdx.x;            // 0..63
    int g = w >> 1;                  // gate 0..3 (i,f,g,o)
    int bh = w & 1;                  // batch half
    int lr = l & 15, hi = l >> 4;    // hi 0..3

    // persistent weights: wrow = g*1024 + bid*16 + lr ; k = ks*32 + hi*8 + j
    const bf16_t* wp = Whh + (size_t)(((g << 10) + (bid << 4) + lr)) * H_ + (hi << 3);
    bf16x8 wf[32];
#pragma unroll
    for (int ks = 0; ks < 32; ++ks) wf[ks] = *(const bf16x8*)(wp + ks * 32);

    // update-phase identity: thread -> (batch b, local col)
    int ub = tid >> 4, uc = tid & 15;
    int hcol = (bid << 4) + uc;
    float bt0 = bih[hcol] + bhh[hcol];
    float bt1 = bih[1024 + hcol] + bhh[1024 + hcol];
    float bt2 = bih[2048 + hcol] + bhh[2048 + hcol];
    float bt3 = bih[3072 + hcol] + bhh[3072 + hcol];
    const float* xp = xw + ((size_t)ub << 18) + hcol;   // + t*4096 per step
    float cst = 0.f;

    int abatch = (bh << 4) + lr;     // A-fragment batch row for this lane

    for (int t = 0; t < T_; ++t) {
        // prefetch xw for this step (independent of h, overlaps MFMA phase)
        const float* xq = xp + ((size_t)t << 12);
        float xv0 = xq[0], xv1 = xq[1024], xv2 = xq[2048], xv3 = xq[3072];

        const bf16_t* ha = (t == 0)
            ? h0 + ((size_t)abatch << 10) + (hi << 3)
            : h_all + ((size_t)(((abatch << 6) + (t - 1))) << 10) + (hi << 3);

        f32x4 ac0 = {}, ac1 = {}, ac2 = {}, ac3 = {};
#pragma unroll
        for (int ks = 0; ks < 32; ks += 4) {
            bf16x8 a0 = cload16(ha + (ks + 0) * 32);
            bf16x8 a1 = cload16(ha + (ks + 1) * 32);
            bf16x8 a2 = cload16(ha + (ks + 2) * 32);
            bf16x8 a3 = cload16(ha + (ks + 3) * 32);
            ac0 = __builtin_amdgcn_mfma_f32_16x16x32_bf16(a0, wf[ks + 0], ac0, 0, 0, 0);
            ac1 = __builtin_amdgcn_mfma_f32_16x16x32_bf16(a1, wf[ks + 1], ac1, 0, 0, 0);
            ac2 = __builtin_amdgcn_mfma_f32_16x16x32_bf16(a2, wf[ks + 2], ac2, 0, 0, 0);
            ac3 = __builtin_amdgcn_mfma_f32_16x16x32_bf16(a3, wf[ks + 3], ac3, 0, 0, 0);
        }
        f32x4 acc;
#pragma unroll
        for (int r = 0; r < 4; ++r) acc[r] = (ac0[r] + ac1[r]) + (ac2[r] + ac3[r]);

        // C: col = l&15 (local W-row), row = hi*4+r (batch within half)
#pragma unroll
        for (int r = 0; r < 4; ++r)
            lds_g[(bh << 4) + (hi << 2) + r][(g << 4) + lr] = acc[r];
        __syncthreads();

        // cell update: thread (ub, uc)
        {
            float xi = lds_g[ub][uc]      + xv0 + bt0;
            float xf = lds_g[ub][16 + uc] + xv1 + bt1;
            float xg = lds_g[ub][32 + uc] + xv2 + bt2;
            float xo = lds_g[ub][48 + uc] + xv3 + bt3;
            float ig = 1.f / (1.f + __expf(-xi));
            float fg = 1.f / (1.f + __expf(-xf));
            float gg = tanhf(xg);
            float og = 1.f / (1.f + __expf(-xo));
            float cn = fg * cst + ig * gg;
            cst = cn;
            union { bf16_t b; unsigned short u; } hb;
            hb.b = (bf16_t)(og * tanhf(cn));
            __hip_atomic_store((unsigned short*)(h_all + ((size_t)((ub << 6) + t) << 10) + hcol),
                               hb.u, __ATOMIC_RELAXED, __HIP_MEMORY_SCOPE_AGENT);
        }
        __syncthreads();   // all waves drain vmcnt -> h stores at coherence point

        if (t < T_ - 1) {
            if (tid == 0)
                __hip_atomic_store(flags + bid * 16, (unsigned)(t + 1),
                                   __ATOMIC_RELAXED, __HIP_MEMORY_SCOPE_AGENT);
            if (tid < 64) {
                int guard = 0;
                while (__hip_atomic_load(flags + tid * 16, __ATOMIC_RELAXED,
                                         __HIP_MEMORY_SCOPE_AGENT) < (unsigned)(t + 1)) {
                    __builtin_amdgcn_s_sleep(1);
                    if (++guard > (1 << 16)) break;   // bounded: fail visibly, never hang
                }
            }
            __syncthreads();
        }
    }
}

// ---------------- LSE partial reduce: lse[m] = logsumexp over col-blocks ----------------
__global__ __launch_bounds__(256) void k_lse2(const float* __restrict__ part,
                                              float* __restrict__ lse, int nbn) {
    int row = blockIdx.x * 4 + (threadIdx.x >> 6);
    int l = threadIdx.x & 63;
    float m = -1e30f, s = 0.f;
    for (int i = l; i < nbn; i += 64) {
        const float* p = part + ((size_t)row * nbn + i) * 2;
        float pm = p[0], ps = p[1];
        float nm = fmaxf(m, pm);
        s = s * __expf(m - nm) + ps * __expf(pm - nm);
        m = nm;
    }
#pragma unroll
    for (int off = 1; off < 64; off <<= 1) {
        float m2 = __shfl_xor(m, off);
        float s2 = __shfl_xor(s, off);
        float nm = fmaxf(m, m2);
        s = s * __expf(m - nm) + s2 * __expf(m2 - nm);
        m = nm;
    }
    if (l == 0) lse[row] = m + __logf(s);
}

// ---------------- subtract pass ----------------
__global__ __launch_bounds__(256) void k_sub(float* __restrict__ out,
                                             const float* __restrict__ lse) {
    int m = blockIdx.x, tid = threadIdx.x;
    float L = lse[m];
    f32x4* row = (f32x4*)(out + (size_t)m * V_);
    for (int i = tid; i < V_ / 4; i += 256) {
        f32x4 v = row[i];
        v[0] -= L; v[1] -= L; v[2] -= L; v[3] -= L;
        row[i] = v;
    }
}

// ---------------- launch ----------------
extern "C" void kernel_launch(void* const* d_in, const int* in_sizes, int n_in,
                              void* d_out, int out_size, void* d_ws, size_t ws_size,
                              hipStream_t stream) {
    const float* isequence = (const float*)d_in[0];  // [B][T][D]
    const float* hidden    = (const float*)d_in[1];  // [B][H]
    const float* W_ih      = (const float*)d_in[2];  // [4H][D]
    const float* W_hh      = (const float*)d_in[3];  // [4H][H]
    const float* b_ih      = (const float*)d_in[4];
    const float* b_hh      = (const float*)d_in[5];
    const float* W_lin     = (const float*)d_in[6];  // [V][H]
    const float* b_lin     = (const float*)d_in[7];
    float* out = (float*)d_out;

    int nbn = (V_ + 127) / 128;  // 157

    auto pad = [](size_t x) { return (x + 255) & ~(size_t)255; };
    const size_t SZ_HALL = (size_t)B_ * T_ * H_ * 2;          // 4 MB
    const size_t SZ_WLIN = (size_t)V_ * H_ * 2;               // 41 MB
    const size_t SZ_FLG  = (size_t)64 * 16 * 4;               // 4 KB
    const size_t SZ_PART = (size_t)B_ * T_ * nbn * 2 * 4;     // 2.6 MB
    const size_t SZ_LSE  = (size_t)B_ * T_ * 4;               // 8 KB
    const size_t SZ_X    = (size_t)B_ * T_ * D_ * 2;          // 2 MB
    const size_t SZ_WIH  = (size_t)4 * H_ * D_ * 2;           // 4 MB
    const size_t SZ_WHH  = (size_t)4 * H_ * H_ * 2;           // 8 MB
    const size_t SZ_H0   = (size_t)B_ * H_ * 2;               // 64 KB
    const size_t SZ_XW   = (size_t)B_ * T_ * 4 * H_ * 4;      // 32 MB (f32)
    size_t needB = pad(SZ_HALL) + pad(SZ_WLIN) + pad(SZ_FLG) + pad(SZ_PART) + pad(SZ_LSE);
    size_t needA = pad(SZ_X) + pad(SZ_WIH) + pad(SZ_WHH) + pad(SZ_H0) + pad(SZ_XW);

    char* wsb = (char*)d_ws;
    // group B lives until after the logits GEMM; group A is dead before d_out's
    // first write, so it can overlay d_out when ws is small.
    char* arenaA = (ws_size >= needA + needB) ? (wsb + needB) : (char*)d_out;

    bf16_t*   h_all   = (bf16_t*)wsb;
    bf16_t*   wlin_bf = (bf16_t*)(wsb + pad(SZ_HALL));
    unsigned* flags   = (unsigned*)(wsb + pad(SZ_HALL) + pad(SZ_WLIN));
    float*    partb   = (float*)(wsb + pad(SZ_HALL) + pad(SZ_WLIN) + pad(SZ_FLG));
    float*    lse     = (float*)(wsb + pad(SZ_HALL) + pad(SZ_WLIN) + pad(SZ_FLG) + pad(SZ_PART));
    bf16_t*   x_bf    = (bf16_t*)arenaA;
    bf16_t*   wih_bf  = (bf16_t*)(arenaA + pad(SZ_X));
    bf16_t*   whh_bf  = (bf16_t*)(arenaA + pad(SZ_X) + pad(SZ_WIH));
    bf16_t*   h0_bf   = (bf16_t*)(arenaA + pad(SZ_X) + pad(SZ_WIH) + pad(SZ_WHH));
    float*    xw      = (float*)(arenaA + pad(SZ_X) + pad(SZ_WIH) + pad(SZ_WHH) + pad(SZ_H0));

    // casts + flag zeroing
    k_cast<<<(B_ * T_ * D_ / 8 + 255) / 256, 256, 0, stream>>>(isequence, x_bf, B_ * T_ * D_ / 8);
    k_cast<<<(V_ * H_ / 8 + 255) / 256, 256, 0, stream>>>(W_lin, wlin_bf, V_ * H_ / 8);
    k_cast<<<(4 * H_ * D_ / 8 + 255) / 256, 256, 0, stream>>>(W_ih, wih_bf, 4 * H_ * D_ / 8);
    k_cast<<<(4 * H_ * H_ / 8 + 255) / 256, 256, 0, stream>>>(W_hh, whh_bf, 4 * H_ * H_ / 8);
    k_cast<<<(B_ * H_ / 8 + 255) / 256, 256, 0, stream>>>(hidden, h0_bf, B_ * H_ / 8);
    hipMemsetAsync(flags, 0, SZ_FLG, stream);

    // xw[m][4H] = x[m][:] @ W_ih^T   (M=2048, N=4096, K=512), grid 512 = 8*64
    k_gemm_t<false, false, false><<<32 * 16, 256, 0, stream>>>(x_bf, D_, wih_bf, D_, D_ / 64,
                                                               nullptr, xw, 4 * H_, 4 * H_, 32,
                                                               64, nullptr);

    // persistent recurrence (64 blocks; cooperative for co-residency)
    {
        const bf16_t* a0 = h0_bf; const bf16_t* a1 = whh_bf; const float* a2 = xw;
        const float* a3 = b_ih; const float* a4 = b_hh; bf16_t* a5 = h_all;
        unsigned* a6 = flags;
        void* kargs[] = {&a0, &a1, &a2, &a3, &a4, &a5, &a6};
        hipLaunchCooperativeKernel((void*)k_recur, dim3(64), dim3(512), kargs, 0, stream);
    }

    // logits GEMM (M=2048, N=20096, K=1024) + bias + LSE partials, grid 2512 = 8*314
    k_gemm_t<true, true, true><<<nbn * (B_ * T_ / 128), 256, 0, stream>>>(h_all, H_, wlin_bf, H_,
                                                                          H_ / 64, b_lin, out, V_,
                                                                          V_, nbn, nbn * 16 / 8,
                                                                          partb);
    // LSE reduce + subtract
    k_lse2<<<B_ * T_ / 4, 256, 0, stream>>>(partb, lse, nbn);
    k_sub<<<B_ * T_, 256, 0, stream>>>(out, lse);
}

// Round 6
// 1110.026 us; speedup vs baseline: 1.4063x; 1.4063x over previous
//
#include <hip/hip_runtime.h>
#include <hip/hip_bf16.h>
#include <cmath>

typedef __bf16 bf16_t;
typedef bf16_t bf16x8 __attribute__((ext_vector_type(8)));
typedef float f32x4 __attribute__((ext_vector_type(4)));
typedef unsigned long long ull_t;

#define B_ 32
#define T_ 64
#define D_ 512
#define H_ 1024
#define V_ 20000

// ---------------- fused 5-way cast ----------------
struct Cast5 {
    const float* s[5];
    bf16_t* d[5];
    int n[5];          // counts in 8-element units
};

__global__ __launch_bounds__(256) void k_cast5(Cast5 a, int total) {
    int i = blockIdx.x * 256 + threadIdx.x;
    if (i >= total) return;
#pragma unroll
    for (int s = 0; s < 5; ++s) {
        if (i < a.n[s]) {
            const f32x4* sv = (const f32x4*)a.s[s] + (size_t)i * 2;
            f32x4 v0 = sv[0], v1 = sv[1];
            bf16x8 o;
            o[0] = (bf16_t)v0[0]; o[1] = (bf16_t)v0[1]; o[2] = (bf16_t)v0[2]; o[3] = (bf16_t)v0[3];
            o[4] = (bf16_t)v1[0]; o[5] = (bf16_t)v1[1]; o[6] = (bf16_t)v1[2]; o[7] = (bf16_t)v1[3];
            *((bf16x8*)a.d[s] + i) = o;
            return;
        }
        i -= a.n[s];
    }
}

// ---------------- async global->LDS helper ----------------
__device__ __forceinline__ void gl_lds16(const bf16_t* g, bf16_t* l) {
    __builtin_amdgcn_global_load_lds(
        (const __attribute__((address_space(1))) unsigned int*)g,
        (__attribute__((address_space(3))) unsigned int*)l, 16, 0, 0);
}

// coherent (agent-scope, L2-bypassing) 16-B load as 2x8B atomics
__device__ __forceinline__ bf16x8 cload16(const bf16_t* p) {
    union { ull_t u[2]; bf16x8 v; } r;
    r.u[0] = __hip_atomic_load((const ull_t*)p,     __ATOMIC_RELAXED, __HIP_MEMORY_SCOPE_AGENT);
    r.u[1] = __hip_atomic_load((const ull_t*)p + 1, __ATOMIC_RELAXED, __HIP_MEMORY_SCOPE_AGENT);
    return r.v;
}

// ---------------- tiled GEMM: out[M x N] = A[M x K] * Bt[N x K]^T (+bias, +LSE partials) ----
// 128x128 block tile, BK=64, 4 waves (2x2), 4x4 fragments/wave, LDS-staged.
// XCD-aware bijective swizzle (grid divisible by 8; cpx = grid/8).
// If LSE: also emits per-(row, col-block) (max, sumexp) partials to `part`.
template<bool EDGE, bool BIAS, bool LSE>
__global__ __launch_bounds__(256) void k_gemm_t(const bf16_t* __restrict__ A, int lda,
                                                const bf16_t* __restrict__ Bt, int ldb,
                                                int nkt, const float* __restrict__ bias,
                                                float* __restrict__ out, int ldo,
                                                int nmax, int nbn, int cpx,
                                                float* __restrict__ part) {
    __shared__ bf16_t lA[128 * 64];
    __shared__ bf16_t lB[128 * 64];
    __shared__ float lds_ls[128][2][2];
    int bid = (blockIdx.x & 7) * cpx + (blockIdx.x >> 3);
    int bn = bid % nbn, bm = bid / nbn;
    int tid = threadIdx.x, w = tid >> 6, l = tid & 63;
    int wm = w >> 1, wn = w & 1;
    int lr = l & 15, lk = (l >> 4) << 3;
    int r0 = bm << 7, c0 = bn << 7;
    int chunkrow = l >> 3;
    int chunkcol = (l & 7) << 3;

    const bf16_t* srcA[4];
    const bf16_t* srcB[4];
#pragma unroll
    for (int i = 0; i < 4; ++i) {
        int rowt = ((w << 2) + i) << 3;
        int ra = r0 + rowt + chunkrow;
        srcA[i] = A + (size_t)ra * lda + chunkcol;
        int rb = c0 + rowt + chunkrow;
        if (EDGE) rb = rb < nmax ? rb : nmax - 1;
        srcB[i] = Bt + (size_t)rb * ldb + chunkcol;
    }

    f32x4 acc[4][4] = {};
    for (int kt = 0; kt < nkt; ++kt) {
        __syncthreads();
#pragma unroll
        for (int i = 0; i < 4; ++i) {
            gl_lds16(srcA[i] + (kt << 6), lA + ((((w << 2) + i)) << 9));
            gl_lds16(srcB[i] + (kt << 6), lB + ((((w << 2) + i)) << 9));
        }
        __syncthreads();
#pragma unroll
        for (int kk = 0; kk < 2; ++kk) {
            bf16x8 af[4], bfr[4];
#pragma unroll
            for (int i = 0; i < 4; ++i)
                af[i] = *(const bf16x8*)&lA[(((wm << 6) + (i << 4) + lr) << 6) + (kk << 5) + lk];
#pragma unroll
            for (int j = 0; j < 4; ++j)
                bfr[j] = *(const bf16x8*)&lB[(((wn << 6) + (j << 4) + lr) << 6) + (kk << 5) + lk];
#pragma unroll
            for (int i = 0; i < 4; ++i)
#pragma unroll
                for (int j = 0; j < 4; ++j)
                    acc[i][j] = __builtin_amdgcn_mfma_f32_16x16x32_bf16(af[i], bfr[j], acc[i][j], 0, 0, 0);
        }
    }

    int crow = (l >> 4) << 2;
    float bl[4]; int colv[4]; bool ok[4];
#pragma unroll
    for (int j = 0; j < 4; ++j) {
        int col = c0 + (wn << 6) + (j << 4) + lr;
        colv[j] = col;
        ok[j] = (!EDGE) || (col < nmax);
        bl[j] = (BIAS && ok[j]) ? bias[col] : 0.f;
    }
#pragma unroll
    for (int i = 0; i < 4; ++i) {
#pragma unroll
        for (int r = 0; r < 4; ++r) {
            int rowloc = (wm << 6) + (i << 4) + crow + r;
            int row = r0 + rowloc;
            float v[4]; float mx = -1e30f;
#pragma unroll
            for (int j = 0; j < 4; ++j) {
                if (ok[j]) {
                    v[j] = acc[i][j][r] + bl[j];
                    out[(size_t)row * ldo + colv[j]] = v[j];
                    mx = fmaxf(mx, v[j]);
                }
            }
            if (LSE) {
                float sm = 0.f;
#pragma unroll
                for (int j = 0; j < 4; ++j)
                    if (ok[j]) sm += __expf(v[j] - mx);
#pragma unroll
                for (int off = 1; off < 16; off <<= 1) {
                    float m2 = __shfl_xor(mx, off);
                    float s2 = __shfl_xor(sm, off);
                    float nm = fmaxf(mx, m2);
                    sm = sm * __expf(mx - nm) + s2 * __expf(m2 - nm);
                    mx = nm;
                }
                if ((l & 15) == 0) { lds_ls[rowloc][wn][0] = mx; lds_ls[rowloc][wn][1] = sm; }
            }
        }
    }
    if (LSE) {
        __syncthreads();
        if (tid < 128) {
            float m0 = lds_ls[tid][0][0], s0 = lds_ls[tid][0][1];
            float m1 = lds_ls[tid][1][0], s1 = lds_ls[tid][1][1];
            float nm = fmaxf(m0, m1);
            float s = s0 * __expf(m0 - nm) + s1 * __expf(m1 - nm);
            float* pp = part + ((size_t)(r0 + tid) * nbn + bn) * 2;
            pp[0] = nm; pp[1] = s;
        }
    }
}

// ---------------- persistent LSTM recurrence, dataflow flags (no barrier) ----------------
// 256 blocks x 512 threads (cooperative launch for co-residency; no grid.sync).
// Block bid owns gate-cols gidx = g*1024 + bid*4 + c (g=0..3, c=0..3); wave w owns
// K-slice [128w,128w+128). W fragments persist in registers. Per step:
//   wave poll: flags[32w..32w+32) >= t  (its producers)  ->  coherent h loads
//   8 MFMA -> LDS partial reduce -> gsum -> cell update (wave 0, lanes<32)
//   h store (agent) -> vmcnt(0) -> flags[bid]=t+1  (single store, own 4B slot)
// No RMW chain, no global barrier, blocks skew freely; flags monotonic.
__global__ __launch_bounds__(512) void k_recur(const bf16_t* __restrict__ h0,
                                               const bf16_t* __restrict__ Whh,   // [4096][1024]
                                               const float* __restrict__ xw,     // [2048][4096]
                                               const float* __restrict__ bih,
                                               const float* __restrict__ bhh,
                                               bf16_t* __restrict__ h_all,       // [2048][1024], m=b*64+t
                                               unsigned* __restrict__ flags) {   // [256] u32
    __shared__ float lds_part[8][32][17];
    __shared__ float lds_g[32][17];
    int tid = threadIdx.x, w = tid >> 6, l = tid & 63;
    int bid = blockIdx.x;
    int lr = l & 15, lk = (l >> 4) << 3;
    int kbase = w << 7;

    // persistent W fragments: output col n = lr -> W-row = (n>>2)*1024 + bid*4 + (n&3)
    int wrow = ((lr >> 2) << 10) + (bid << 2) + (lr & 3);
    const bf16_t* wp = Whh + (size_t)wrow * H_ + kbase + lk;
    bf16x8 wf0 = *(const bf16x8*)(wp);
    bf16x8 wf1 = *(const bf16x8*)(wp + 32);
    bf16x8 wf2 = *(const bf16x8*)(wp + 64);
    bf16x8 wf3 = *(const bf16x8*)(wp + 96);

    // reduce-phase identity
    int rb = tid >> 4, rn = tid & 15;
    int gidx = ((rn >> 2) << 10) + (bid << 2) + (rn & 3);
    float btot = bih[gidx] + bhh[gidx];

    // cell state (wave 0, lanes 0..31; batch = lane, 4 cols)
    float creg[4] = {0.f, 0.f, 0.f, 0.f};

    int fidx = (w << 5) + (l & 31);   // this wave's producer-flag index

    for (int t = 0; t < T_; ++t) {
        // xw prefetch (independent of h)
        float xval = xw[(size_t)(((rb << 6) + t) << 12) + gidx];

        if (t > 0) {
            unsigned tv = (unsigned)t;
            int guard = 0;
            while (true) {
                unsigned v = __hip_atomic_load(flags + fidx, __ATOMIC_RELAXED, __HIP_MEMORY_SCOPE_AGENT);
                if (__all((int)(v >= tv))) break;
                __builtin_amdgcn_s_sleep(2);
                if (++guard > (1 << 17)) break;   // bounded: fail visibly, never hang
            }
            asm volatile("" ::: "memory");
        }

        const bf16_t* pa0;
        const bf16_t* pa1;
        if (t == 0) {
            pa0 = h0 + ((size_t)lr << 10) + kbase + lk;
            pa1 = h0 + ((size_t)(lr + 16) << 10) + kbase + lk;
        } else {
            const bf16_t* hb = h_all + ((size_t)(t - 1) << 10);
            pa0 = hb + ((size_t)lr << 16) + kbase + lk;
            pa1 = hb + ((size_t)(lr + 16) << 16) + kbase + lk;
        }

        bf16x8 a00 = cload16(pa0);
        bf16x8 a01 = cload16(pa0 + 32);
        bf16x8 a02 = cload16(pa0 + 64);
        bf16x8 a03 = cload16(pa0 + 96);
        bf16x8 a10 = cload16(pa1);
        bf16x8 a11 = cload16(pa1 + 32);
        bf16x8 a12 = cload16(pa1 + 64);
        bf16x8 a13 = cload16(pa1 + 96);

        f32x4 acc0 = {}, acc1 = {};
        acc0 = __builtin_amdgcn_mfma_f32_16x16x32_bf16(a00, wf0, acc0, 0, 0, 0);
        acc1 = __builtin_amdgcn_mfma_f32_16x16x32_bf16(a10, wf0, acc1, 0, 0, 0);
        acc0 = __builtin_amdgcn_mfma_f32_16x16x32_bf16(a01, wf1, acc0, 0, 0, 0);
        acc1 = __builtin_amdgcn_mfma_f32_16x16x32_bf16(a11, wf1, acc1, 0, 0, 0);
        acc0 = __builtin_amdgcn_mfma_f32_16x16x32_bf16(a02, wf2, acc0, 0, 0, 0);
        acc1 = __builtin_amdgcn_mfma_f32_16x16x32_bf16(a12, wf2, acc1, 0, 0, 0);
        acc0 = __builtin_amdgcn_mfma_f32_16x16x32_bf16(a03, wf3, acc0, 0, 0, 0);
        acc1 = __builtin_amdgcn_mfma_f32_16x16x32_bf16(a13, wf3, acc1, 0, 0, 0);

        int crow = (l >> 4) << 2;
#pragma unroll
        for (int r = 0; r < 4; ++r) {
            lds_part[w][crow + r][lr]      = acc0[r];
            lds_part[w][16 + crow + r][lr] = acc1[r];
        }
        __syncthreads();   // sync1: partials complete

        float gsum = btot + xval;
#pragma unroll
        for (int ww = 0; ww < 8; ++ww) gsum += lds_part[ww][rb][rn];
        lds_g[rb][rn] = gsum;
        __syncthreads();   // sync2: gate sums complete

        if (w == 0) {
            if (l < 32) {
                union { bf16_t b[4]; ull_t u; } hp;
#pragma unroll
                for (int j = 0; j < 4; ++j) {
                    float xi = lds_g[l][j];
                    float xf = lds_g[l][4 + j];
                    float xg = lds_g[l][8 + j];
                    float xo = lds_g[l][12 + j];
                    float ig = 1.f / (1.f + __expf(-xi));
                    float fg = 1.f / (1.f + __expf(-xf));
                    float gg = tanhf(xg);
                    float og = 1.f / (1.f + __expf(-xo));
                    float cn = fg * creg[j] + ig * gg;
                    creg[j] = cn;
                    hp.b[j] = (bf16_t)(og * tanhf(cn));
                }
                __hip_atomic_store((ull_t*)(h_all + ((size_t)((l << 6) + t) << 10) + (bid << 2)),
                                   hp.u, __ATOMIC_RELAXED, __HIP_MEMORY_SCOPE_AGENT);
            }
            if (t < T_ - 1) {
                asm volatile("s_waitcnt vmcnt(0)" ::: "memory");   // h stores acked at coherence point
                if (l == 0)
                    __hip_atomic_store(flags + bid, (unsigned)(t + 1),
                                       __ATOMIC_RELAXED, __HIP_MEMORY_SCOPE_AGENT);
            }
        }
        // no block-wide barrier needed: lds_part WAR is ordered by sync2 (reads
        // precede it), lds_g next write is ordered by next iteration's sync1.
    }
}

// ---------------- LSE partial reduce: lse[m] = logsumexp over col-blocks ----------------
__global__ __launch_bounds__(256) void k_lse2(const float* __restrict__ part,
                                              float* __restrict__ lse, int nbn) {
    int row = blockIdx.x * 4 + (threadIdx.x >> 6);
    int l = threadIdx.x & 63;
    float m = -1e30f, s = 0.f;
    for (int i = l; i < nbn; i += 64) {
        const float* p = part + ((size_t)row * nbn + i) * 2;
        float pm = p[0], ps = p[1];
        float nm = fmaxf(m, pm);
        s = s * __expf(m - nm) + ps * __expf(pm - nm);
        m = nm;
    }
#pragma unroll
    for (int off = 1; off < 64; off <<= 1) {
        float m2 = __shfl_xor(m, off);
        float s2 = __shfl_xor(s, off);
        float nm = fmaxf(m, m2);
        s = s * __expf(m - nm) + s2 * __expf(m2 - nm);
        m = nm;
    }
    if (l == 0) lse[row] = m + __logf(s);
}

// ---------------- subtract pass ----------------
__global__ __launch_bounds__(256) void k_sub(float* __restrict__ out,
                                             const float* __restrict__ lse) {
    int m = blockIdx.x, tid = threadIdx.x;
    float L = lse[m];
    f32x4* row = (f32x4*)(out + (size_t)m * V_);
    for (int i = tid; i < V_ / 4; i += 256) {
        f32x4 v = row[i];
        v[0] -= L; v[1] -= L; v[2] -= L; v[3] -= L;
        row[i] = v;
    }
}

// ---------------- launch ----------------
extern "C" void kernel_launch(void* const* d_in, const int* in_sizes, int n_in,
                              void* d_out, int out_size, void* d_ws, size_t ws_size,
                              hipStream_t stream) {
    const float* isequence = (const float*)d_in[0];  // [B][T][D]
    const float* hidden    = (const float*)d_in[1];  // [B][H]
    const float* W_ih      = (const float*)d_in[2];  // [4H][D]
    const float* W_hh      = (const float*)d_in[3];  // [4H][H]
    const float* b_ih      = (const float*)d_in[4];
    const float* b_hh      = (const float*)d_in[5];
    const float* W_lin     = (const float*)d_in[6];  // [V][H]
    const float* b_lin     = (const float*)d_in[7];
    float* out = (float*)d_out;

    int nbn = (V_ + 127) / 128;  // 157

    auto pad = [](size_t x) { return (x + 255) & ~(size_t)255; };
    const size_t SZ_HALL = (size_t)B_ * T_ * H_ * 2;          // 4 MB
    const size_t SZ_WLIN = (size_t)V_ * H_ * 2;               // 41 MB
    const size_t SZ_FLG  = (size_t)256 * 4;                   // 1 KB
    const size_t SZ_PART = (size_t)B_ * T_ * nbn * 2 * 4;     // 2.6 MB
    const size_t SZ_LSE  = (size_t)B_ * T_ * 4;               // 8 KB
    const size_t SZ_X    = (size_t)B_ * T_ * D_ * 2;          // 2 MB
    const size_t SZ_WIH  = (size_t)4 * H_ * D_ * 2;           // 4 MB
    const size_t SZ_WHH  = (size_t)4 * H_ * H_ * 2;           // 8 MB
    const size_t SZ_H0   = (size_t)B_ * H_ * 2;               // 64 KB
    const size_t SZ_XW   = (size_t)B_ * T_ * 4 * H_ * 4;      // 32 MB (f32)
    size_t needB = pad(SZ_HALL) + pad(SZ_WLIN) + pad(SZ_FLG) + pad(SZ_PART) + pad(SZ_LSE);
    size_t needA = pad(SZ_X) + pad(SZ_WIH) + pad(SZ_WHH) + pad(SZ_H0) + pad(SZ_XW);

    char* wsb = (char*)d_ws;
    // group B lives until after the logits GEMM; group A is dead before d_out's
    // first write, so it can overlay d_out when ws is small.
    char* arenaA = (ws_size >= needA + needB) ? (wsb + needB) : (char*)d_out;

    bf16_t*   h_all   = (bf16_t*)wsb;
    bf16_t*   wlin_bf = (bf16_t*)(wsb + pad(SZ_HALL));
    unsigned* flags   = (unsigned*)(wsb + pad(SZ_HALL) + pad(SZ_WLIN));
    float*    partb   = (float*)(wsb + pad(SZ_HALL) + pad(SZ_WLIN) + pad(SZ_FLG));
    float*    lse     = (float*)(wsb + pad(SZ_HALL) + pad(SZ_WLIN) + pad(SZ_FLG) + pad(SZ_PART));
    bf16_t*   x_bf    = (bf16_t*)arenaA;
    bf16_t*   wih_bf  = (bf16_t*)(arenaA + pad(SZ_X));
    bf16_t*   whh_bf  = (bf16_t*)(arenaA + pad(SZ_X) + pad(SZ_WIH));
    bf16_t*   h0_bf   = (bf16_t*)(arenaA + pad(SZ_X) + pad(SZ_WIH) + pad(SZ_WHH));
    float*    xw      = (float*)(arenaA + pad(SZ_X) + pad(SZ_WIH) + pad(SZ_WHH) + pad(SZ_H0));

    // fused casts (wlin first: most blocks take the first branch)
    Cast5 ca;
    ca.s[0] = W_lin;     ca.d[0] = wlin_bf; ca.n[0] = V_ * H_ / 8;
    ca.s[1] = W_hh;      ca.d[1] = whh_bf;  ca.n[1] = 4 * H_ * H_ / 8;
    ca.s[2] = W_ih;      ca.d[2] = wih_bf;  ca.n[2] = 4 * H_ * D_ / 8;
    ca.s[3] = isequence; ca.d[3] = x_bf;    ca.n[3] = B_ * T_ * D_ / 8;
    ca.s[4] = hidden;    ca.d[4] = h0_bf;   ca.n[4] = B_ * H_ / 8;
    int total8 = ca.n[0] + ca.n[1] + ca.n[2] + ca.n[3] + ca.n[4];
    k_cast5<<<(total8 + 255) / 256, 256, 0, stream>>>(ca, total8);
    hipMemsetAsync(flags, 0, SZ_FLG, stream);

    // xw[m][4H] = x[m][:] @ W_ih^T   (M=2048, N=4096, K=512), grid 512 = 8*64
    k_gemm_t<false, false, false><<<32 * 16, 256, 0, stream>>>(x_bf, D_, wih_bf, D_, D_ / 64,
                                                               nullptr, xw, 4 * H_, 4 * H_, 32,
                                                               64, nullptr);

    // persistent recurrence (256 blocks; cooperative for co-residency)
    {
        const bf16_t* a0 = h0_bf; const bf16_t* a1 = whh_bf; const float* a2 = xw;
        const float* a3 = b_ih; const float* a4 = b_hh; bf16_t* a5 = h_all;
        unsigned* a6 = flags;
        void* kargs[] = {&a0, &a1, &a2, &a3, &a4, &a5, &a6};
        hipLaunchCooperativeKernel((void*)k_recur, dim3(256), dim3(512), kargs, 0, stream);
    }

    // logits GEMM (M=2048, N=20096, K=1024) + bias + LSE partials, grid 2512 = 8*314
    k_gemm_t<true, true, true><<<nbn * (B_ * T_ / 128), 256, 0, stream>>>(h_all, H_, wlin_bf, H_,
                                                                          H_ / 64, b_lin, out, V_,
                                                                          V_, nbn, nbn * 16 / 8,
                                                                          partb);
    // LSE reduce + subtract
    k_lse2<<<B_ * T_ / 4, 256, 0, stream>>>(partb, lse, nbn);
    k_sub<<<B_ * T_, 256, 0, stream>>>(out, lse);
}

// Round 7
// 764.393 us; speedup vs baseline: 2.0422x; 1.4522x over previous
//
#include <hip/hip_runtime.h>
#include <hip/hip_bf16.h>
#include <cmath>

typedef __bf16 bf16_t;
typedef bf16_t bf16x8 __attribute__((ext_vector_type(8)));
typedef float f32x4 __attribute__((ext_vector_type(4)));
typedef unsigned long long ull_t;

#define B_ 32
#define T_ 64
#define D_ 512
#define H_ 1024
#define V_ 20000

// ---------------- fused 5-way cast ----------------
struct Cast5 {
    const float* s[5];
    bf16_t* d[5];
    int n[5];          // counts in 8-element units
};

__global__ __launch_bounds__(256) void k_cast5(Cast5 a, int total) {
    int i = blockIdx.x * 256 + threadIdx.x;
    if (i >= total) return;
#pragma unroll
    for (int s = 0; s < 5; ++s) {
        if (i < a.n[s]) {
            const f32x4* sv = (const f32x4*)a.s[s] + (size_t)i * 2;
            f32x4 v0 = sv[0], v1 = sv[1];
            bf16x8 o;
            o[0] = (bf16_t)v0[0]; o[1] = (bf16_t)v0[1]; o[2] = (bf16_t)v0[2]; o[3] = (bf16_t)v0[3];
            o[4] = (bf16_t)v1[0]; o[5] = (bf16_t)v1[1]; o[6] = (bf16_t)v1[2]; o[7] = (bf16_t)v1[3];
            *((bf16x8*)a.d[s] + i) = o;
            return;
        }
        i -= a.n[s];
    }
}

// ---------------- async global->LDS helper ----------------
__device__ __forceinline__ void gl_lds16(const bf16_t* g, bf16_t* l) {
    __builtin_amdgcn_global_load_lds(
        (const __attribute__((address_space(1))) unsigned int*)g,
        (__attribute__((address_space(3))) unsigned int*)l, 16, 0, 0);
}

// coherent (agent-scope, L2-bypassing) 16-B load as 2x8B atomics
__device__ __forceinline__ bf16x8 cload16(const bf16_t* p) {
    union { ull_t u[2]; bf16x8 v; } r;
    r.u[0] = __hip_atomic_load((const ull_t*)p,     __ATOMIC_RELAXED, __HIP_MEMORY_SCOPE_AGENT);
    r.u[1] = __hip_atomic_load((const ull_t*)p + 1, __ATOMIC_RELAXED, __HIP_MEMORY_SCOPE_AGENT);
    return r.v;
}

// ---------------- tiled GEMM: out[M x N] = A[M x K] * Bt[N x K]^T (+bias, +LSE partials) ----
// 128x128 block tile, BK=64, 4 waves (2x2), 4x4 fragments/wave, LDS-staged.
// XCD-aware bijective swizzle (grid divisible by 8; cpx = grid/8).
// If LSE: also emits per-(row, col-block) (max, sumexp) partials to `part`.
template<bool EDGE, bool BIAS, bool LSE>
__global__ __launch_bounds__(256) void k_gemm_t(const bf16_t* __restrict__ A, int lda,
                                                const bf16_t* __restrict__ Bt, int ldb,
                                                int nkt, const float* __restrict__ bias,
                                                float* __restrict__ out, int ldo,
                                                int nmax, int nbn, int cpx,
                                                float* __restrict__ part) {
    __shared__ bf16_t lA[128 * 64];
    __shared__ bf16_t lB[128 * 64];
    __shared__ float lds_ls[128][2][2];
    int bid = (blockIdx.x & 7) * cpx + (blockIdx.x >> 3);
    int bn = bid % nbn, bm = bid / nbn;
    int tid = threadIdx.x, w = tid >> 6, l = tid & 63;
    int wm = w >> 1, wn = w & 1;
    int lr = l & 15, lk = (l >> 4) << 3;
    int r0 = bm << 7, c0 = bn << 7;
    int chunkrow = l >> 3;
    int chunkcol = (l & 7) << 3;

    const bf16_t* srcA[4];
    const bf16_t* srcB[4];
#pragma unroll
    for (int i = 0; i < 4; ++i) {
        int rowt = ((w << 2) + i) << 3;
        int ra = r0 + rowt + chunkrow;
        srcA[i] = A + (size_t)ra * lda + chunkcol;
        int rb = c0 + rowt + chunkrow;
        if (EDGE) rb = rb < nmax ? rb : nmax - 1;
        srcB[i] = Bt + (size_t)rb * ldb + chunkcol;
    }

    f32x4 acc[4][4] = {};
    for (int kt = 0; kt < nkt; ++kt) {
        __syncthreads();
#pragma unroll
        for (int i = 0; i < 4; ++i) {
            gl_lds16(srcA[i] + (kt << 6), lA + ((((w << 2) + i)) << 9));
            gl_lds16(srcB[i] + (kt << 6), lB + ((((w << 2) + i)) << 9));
        }
        __syncthreads();
#pragma unroll
        for (int kk = 0; kk < 2; ++kk) {
            bf16x8 af[4], bfr[4];
#pragma unroll
            for (int i = 0; i < 4; ++i)
                af[i] = *(const bf16x8*)&lA[(((wm << 6) + (i << 4) + lr) << 6) + (kk << 5) + lk];
#pragma unroll
            for (int j = 0; j < 4; ++j)
                bfr[j] = *(const bf16x8*)&lB[(((wn << 6) + (j << 4) + lr) << 6) + (kk << 5) + lk];
#pragma unroll
            for (int i = 0; i < 4; ++i)
#pragma unroll
                for (int j = 0; j < 4; ++j)
                    acc[i][j] = __builtin_amdgcn_mfma_f32_16x16x32_bf16(af[i], bfr[j], acc[i][j], 0, 0, 0);
        }
    }

    int crow = (l >> 4) << 2;
    float bl[4]; int colv[4]; bool ok[4];
#pragma unroll
    for (int j = 0; j < 4; ++j) {
        int col = c0 + (wn << 6) + (j << 4) + lr;
        colv[j] = col;
        ok[j] = (!EDGE) || (col < nmax);
        bl[j] = (BIAS && ok[j]) ? bias[col] : 0.f;
    }
#pragma unroll
    for (int i = 0; i < 4; ++i) {
#pragma unroll
        for (int r = 0; r < 4; ++r) {
            int rowloc = (wm << 6) + (i << 4) + crow + r;
            int row = r0 + rowloc;
            float v[4]; float mx = -1e30f;
#pragma unroll
            for (int j = 0; j < 4; ++j) {
                if (ok[j]) {
                    v[j] = acc[i][j][r] + bl[j];
                    out[(size_t)row * ldo + colv[j]] = v[j];
                    mx = fmaxf(mx, v[j]);
                }
            }
            if (LSE) {
                float sm = 0.f;
#pragma unroll
                for (int j = 0; j < 4; ++j)
                    if (ok[j]) sm += __expf(v[j] - mx);
#pragma unroll
                for (int off = 1; off < 16; off <<= 1) {
                    float m2 = __shfl_xor(mx, off);
                    float s2 = __shfl_xor(sm, off);
                    float nm = fmaxf(mx, m2);
                    sm = sm * __expf(mx - nm) + s2 * __expf(m2 - nm);
                    mx = nm;
                }
                if ((l & 15) == 0) { lds_ls[rowloc][wn][0] = mx; lds_ls[rowloc][wn][1] = sm; }
            }
        }
    }
    if (LSE) {
        __syncthreads();
        if (tid < 128) {
            float m0 = lds_ls[tid][0][0], s0 = lds_ls[tid][0][1];
            float m1 = lds_ls[tid][1][0], s1 = lds_ls[tid][1][1];
            float nm = fmaxf(m0, m1);
            float s = s0 * __expf(m0 - nm) + s1 * __expf(m1 - nm);
            float* pp = part + ((size_t)(r0 + tid) * nbn + bn) * 2;
            pp[0] = nm; pp[1] = s;
        }
    }
}

// ---------------- persistent LSTM recurrence v3: LDS-staged h, minimal broadcast ----
// 128 blocks x 512 threads (cooperative for co-residency; no grid.sync).
// Block (cg = bid>>1, bh = bid&1): owns 64 gate-cols (4 gates x 16 h-cols at
// cg*16) and 16 batches (bh*16..+16). W slice (64 rows x 1024) persists in
// registers (64 VGPR/lane). Per step:
//   poll 64 same-half flags (64 lanes parallel) -> stage 16x1024 h-slice into
//   LDS once (coalesced 1KB/wave coherent bursts, XOR-swizzled rows) ->
//   8 waves (gate g, K-half kq) do 16 MFMAs each from LDS -> partials ->
//   cell update (256 threads, fused 2-way K reduce) -> h stores -> barrier
//   (drains vmcnt) -> single flag store.
// Uncached h traffic: 128 blocks x 32 KB = 4 MB/step (was 16 MB).
__global__ __launch_bounds__(512) void k_recur(const bf16_t* __restrict__ h0,     // [32][1024]
                                               const bf16_t* __restrict__ Whh,    // [4096][1024]
                                               const float* __restrict__ xw,      // [2048][4096]
                                               const float* __restrict__ bih,
                                               const float* __restrict__ bhh,
                                               bf16_t* __restrict__ h_all,        // [2048][1024], m=b*64+t
                                               unsigned* __restrict__ flags) {    // [128] u32
    __shared__ bf16_t lds_h[16 * 1024];              // 32 KB, rows XOR-swizzled
    __shared__ float lds_p[2][4][16][16];            // 8 KB partials [kq][g][b][c]
    char* lhb = (char*)lds_h;

    int tid = threadIdx.x, w = tid >> 6, l = tid & 63;
    int bid = blockIdx.x;
    int cg = bid >> 1, bh = bid & 1;
    int g = w >> 1, kq = w & 1;
    int lr = l & 15, hi = l >> 4;

    // persistent W fragments: row = g*1024 + cg*16 + lr; k = kq*512 + kt*32 + hi*8
    const bf16_t* wp = Whh + (size_t)((g << 10) + (cg << 4) + lr) * H_ + (kq << 9) + (hi << 3);
    bf16x8 wf[16];
#pragma unroll
    for (int kt = 0; kt < 16; ++kt) wf[kt] = *(const bf16x8*)(wp + kt * 32);

    // staging identity: chunk ci = it*512+tid -> row = ci>>7, c8 = ci&127
    // cell identity (tid<256): b = tid>>4, c = tid&15
    int bloc = (tid >> 4) & 15;                 // clamped batch-local (valid for all tid)
    int batch = (bh << 4) + bloc;
    int hcol = (cg << 4) + (tid & 15);
    float bt0 = bih[hcol] + bhh[hcol];
    float bt1 = bih[1024 + hcol] + bhh[1024 + hcol];
    float bt2 = bih[2048 + hcol] + bhh[2048 + hcol];
    float bt3 = bih[3072 + hcol] + bhh[3072 + hcol];
    const float* xq = xw + ((size_t)(batch << 6) << 12) + hcol;   // + t*4096 per step
    float cst = 0.f;

    for (int t = 0; t < T_; ++t) {
        // xw prefetch (independent of h; hides under poll)
        const float* xb = xq + ((size_t)t << 12);
        float xv0 = xb[0], xv1 = xb[1024], xv2 = xb[2048], xv3 = xb[3072];

        if (t > 0) {
            unsigned tv = (unsigned)t;
            int guard = 0;
            while (true) {
                unsigned v = __hip_atomic_load(flags + ((l << 1) | bh),
                                               __ATOMIC_RELAXED, __HIP_MEMORY_SCOPE_AGENT);
                if (__all((int)(v >= tv))) break;
                __builtin_amdgcn_s_sleep(2);
                if (++guard > (1 << 17)) break;   // bounded: fail visibly, never hang
            }
            asm volatile("" ::: "memory");
        }

        // stage h-slice: 2048 x 16B chunks, 4 per thread; all loads issued first
        bf16x8 sv[4];
#pragma unroll
        for (int it = 0; it < 4; ++it) {
            int ci = it * 512 + tid;
            int row = ci >> 7, c8 = ci & 127;
            const bf16_t* src = (t == 0)
                ? h0 + ((size_t)((bh << 4) + row) << 10) + (c8 << 3)
                : h_all + ((size_t)((((bh << 4) + row) << 6) + (t - 1)) << 10) + (c8 << 3);
            sv[it] = cload16(src);
        }
#pragma unroll
        for (int it = 0; it < 4; ++it) {
            int ci = it * 512 + tid;
            int row = ci >> 7, c8 = ci & 127;
            *(bf16x8*)(lhb + (((row << 11) + (c8 << 4)) ^ ((row & 7) << 4))) = sv[it];
        }
        __syncthreads();   // lds_h ready (also orders vs prev step's reads)

        // MFMA: wave (g, kq): A row = lr (batch), k = kq*512 + kt*32 + hi*8
        f32x4 acc = {};
#pragma unroll
        for (int kt = 0; kt < 16; ++kt) {
            bf16x8 af = *(const bf16x8*)(lhb +
                (((lr << 11) + (kq << 10) + (kt << 6) + (hi << 4)) ^ ((lr & 7) << 4)));
            acc = __builtin_amdgcn_mfma_f32_16x16x32_bf16(af, wf[kt], acc, 0, 0, 0);
        }
        // C: col = lr (gate-col), row = hi*4+r (batch-local)
#pragma unroll
        for (int r = 0; r < 4; ++r)
            lds_p[kq][g][(hi << 2) + r][lr] = acc[r];
        __syncthreads();   // partials ready

        // cell update: 256 threads, one (batch, h-col) each; fused K-half reduce
        if (tid < 256) {
            int b = tid >> 4, c = tid & 15;
            float xi = lds_p[0][0][b][c] + lds_p[1][0][b][c] + xv0 + bt0;
            float xf = lds_p[0][1][b][c] + lds_p[1][1][b][c] + xv1 + bt1;
            float xg = lds_p[0][2][b][c] + lds_p[1][2][b][c] + xv2 + bt2;
            float xo = lds_p[0][3][b][c] + lds_p[1][3][b][c] + xv3 + bt3;
            float ig = 1.f / (1.f + __expf(-xi));
            float fg = 1.f / (1.f + __expf(-xf));
            float gg = tanhf(xg);
            float og = 1.f / (1.f + __expf(-xo));
            float cn = fg * cst + ig * gg;
            cst = cn;
            union { bf16_t bv; unsigned short u; } hb;
            hb.bv = (bf16_t)(og * tanhf(cn));
            __hip_atomic_store((unsigned short*)(h_all + ((size_t)((batch << 6) + t) << 10) + hcol),
                               hb.u, __ATOMIC_RELAXED, __HIP_MEMORY_SCOPE_AGENT);
        }
        __syncthreads();   // drains vmcnt in all storing waves -> h at coherence point

        if (t < T_ - 1 && tid == 0)
            __hip_atomic_store(flags + bid, (unsigned)(t + 1),
                               __ATOMIC_RELAXED, __HIP_MEMORY_SCOPE_AGENT);
    }
}

// ---------------- LSE partial reduce: lse[m] = logsumexp over col-blocks ----------------
__global__ __launch_bounds__(256) void k_lse2(const float* __restrict__ part,
                                              float* __restrict__ lse, int nbn) {
    int row = blockIdx.x * 4 + (threadIdx.x >> 6);
    int l = threadIdx.x & 63;
    float m = -1e30f, s = 0.f;
    for (int i = l; i < nbn; i += 64) {
        const float* p = part + ((size_t)row * nbn + i) * 2;
        float pm = p[0], ps = p[1];
        float nm = fmaxf(m, pm);
        s = s * __expf(m - nm) + ps * __expf(pm - nm);
        m = nm;
    }
#pragma unroll
    for (int off = 1; off < 64; off <<= 1) {
        float m2 = __shfl_xor(m, off);
        float s2 = __shfl_xor(s, off);
        float nm = fmaxf(m, m2);
        s = s * __expf(m - nm) + s2 * __expf(m2 - nm);
        m = nm;
    }
    if (l == 0) lse[row] = m + __logf(s);
}

// ---------------- subtract pass ----------------
__global__ __launch_bounds__(256) void k_sub(float* __restrict__ out,
                                             const float* __restrict__ lse) {
    int m = blockIdx.x, tid = threadIdx.x;
    float L = lse[m];
    f32x4* row = (f32x4*)(out + (size_t)m * V_);
    for (int i = tid; i < V_ / 4; i += 256) {
        f32x4 v = row[i];
        v[0] -= L; v[1] -= L; v[2] -= L; v[3] -= L;
        row[i] = v;
    }
}

// ---------------- launch ----------------
extern "C" void kernel_launch(void* const* d_in, const int* in_sizes, int n_in,
                              void* d_out, int out_size, void* d_ws, size_t ws_size,
                              hipStream_t stream) {
    const float* isequence = (const float*)d_in[0];  // [B][T][D]
    const float* hidden    = (const float*)d_in[1];  // [B][H]
    const float* W_ih      = (const float*)d_in[2];  // [4H][D]
    const float* W_hh      = (const float*)d_in[3];  // [4H][H]
    const float* b_ih      = (const float*)d_in[4];
    const float* b_hh      = (const float*)d_in[5];
    const float* W_lin     = (const float*)d_in[6];  // [V][H]
    const float* b_lin     = (const float*)d_in[7];
    float* out = (float*)d_out;

    int nbn = (V_ + 127) / 128;  // 157

    auto pad = [](size_t x) { return (x + 255) & ~(size_t)255; };
    const size_t SZ_HALL = (size_t)B_ * T_ * H_ * 2;          // 4 MB
    const size_t SZ_WLIN = (size_t)V_ * H_ * 2;               // 41 MB
    const size_t SZ_FLG  = (size_t)128 * 4;                   // 512 B
    const size_t SZ_PART = (size_t)B_ * T_ * nbn * 2 * 4;     // 2.6 MB
    const size_t SZ_LSE  = (size_t)B_ * T_ * 4;               // 8 KB
    const size_t SZ_X    = (size_t)B_ * T_ * D_ * 2;          // 2 MB
    const size_t SZ_WIH  = (size_t)4 * H_ * D_ * 2;           // 4 MB
    const size_t SZ_WHH  = (size_t)4 * H_ * H_ * 2;           // 8 MB
    const size_t SZ_H0   = (size_t)B_ * H_ * 2;               // 64 KB
    const size_t SZ_XW   = (size_t)B_ * T_ * 4 * H_ * 4;      // 32 MB (f32)
    size_t needB = pad(SZ_HALL) + pad(SZ_WLIN) + pad(SZ_FLG) + pad(SZ_PART) + pad(SZ_LSE);
    size_t needA = pad(SZ_X) + pad(SZ_WIH) + pad(SZ_WHH) + pad(SZ_H0) + pad(SZ_XW);

    char* wsb = (char*)d_ws;
    // group B lives until after the logits GEMM; group A is dead before d_out's
    // first write, so it can overlay d_out when ws is small.
    char* arenaA = (ws_size >= needA + needB) ? (wsb + needB) : (char*)d_out;

    bf16_t*   h_all   = (bf16_t*)wsb;
    bf16_t*   wlin_bf = (bf16_t*)(wsb + pad(SZ_HALL));
    unsigned* flags   = (unsigned*)(wsb + pad(SZ_HALL) + pad(SZ_WLIN));
    float*    partb   = (float*)(wsb + pad(SZ_HALL) + pad(SZ_WLIN) + pad(SZ_FLG));
    float*    lse     = (float*)(wsb + pad(SZ_HALL) + pad(SZ_WLIN) + pad(SZ_FLG) + pad(SZ_PART));
    bf16_t*   x_bf    = (bf16_t*)arenaA;
    bf16_t*   wih_bf  = (bf16_t*)(arenaA + pad(SZ_X));
    bf16_t*   whh_bf  = (bf16_t*)(arenaA + pad(SZ_X) + pad(SZ_WIH));
    bf16_t*   h0_bf   = (bf16_t*)(arenaA + pad(SZ_X) + pad(SZ_WIH) + pad(SZ_WHH));
    float*    xw      = (float*)(arenaA + pad(SZ_X) + pad(SZ_WIH) + pad(SZ_WHH) + pad(SZ_H0));

    // fused casts
    Cast5 ca;
    ca.s[0] = W_lin;     ca.d[0] = wlin_bf; ca.n[0] = V_ * H_ / 8;
    ca.s[1] = W_hh;      ca.d[1] = whh_bf;  ca.n[1] = 4 * H_ * H_ / 8;
    ca.s[2] = W_ih;      ca.d[2] = wih_bf;  ca.n[2] = 4 * H_ * D_ / 8;
    ca.s[3] = isequence; ca.d[3] = x_bf;    ca.n[3] = B_ * T_ * D_ / 8;
    ca.s[4] = hidden;    ca.d[4] = h0_bf;   ca.n[4] = B_ * H_ / 8;
    int total8 = ca.n[0] + ca.n[1] + ca.n[2] + ca.n[3] + ca.n[4];
    k_cast5<<<(total8 + 255) / 256, 256, 0, stream>>>(ca, total8);
    hipMemsetAsync(flags, 0, SZ_FLG, stream);

    // xw[m][4H] = x[m][:] @ W_ih^T   (M=2048, N=4096, K=512), grid 512 = 8*64
    k_gemm_t<false, false, false><<<32 * 16, 256, 0, stream>>>(x_bf, D_, wih_bf, D_, D_ / 64,
                                                               nullptr, xw, 4 * H_, 4 * H_, 32,
                                                               64, nullptr);

    // persistent recurrence (128 blocks; cooperative for co-residency)
    {
        const bf16_t* a0 = h0_bf; const bf16_t* a1 = whh_bf; const float* a2 = xw;
        const float* a3 = b_ih; const float* a4 = b_hh; bf16_t* a5 = h_all;
        unsigned* a6 = flags;
        void* kargs[] = {&a0, &a1, &a2, &a3, &a4, &a5, &a6};
        hipLaunchCooperativeKernel((void*)k_recur, dim3(128), dim3(512), kargs, 0, stream);
    }

    // logits GEMM (M=2048, N=20096, K=1024) + bias + LSE partials, grid 2512 = 8*314
    k_gemm_t<true, true, true><<<nbn * (B_ * T_ / 128), 256, 0, stream>>>(h_all, H_, wlin_bf, H_,
                                                                          H_ / 64, b_lin, out, V_,
                                                                          V_, nbn, nbn * 16 / 8,
                                                                          partb);
    // LSE reduce + subtract
    k_lse2<<<B_ * T_ / 4, 256, 0, stream>>>(partb, lse, nbn);
    k_sub<<<B_ * T_, 256, 0, stream>>>(out, lse);
}